// Round 3
// baseline (1051.629 us; speedup 1.0000x reference)
//
#include <hip/hip_runtime.h>
#include <hip/hip_bf16.h>
#include <hip/hip_fp16.h>

// GCN 2-layer: h1 = relu(A_hat (x@W1) + b1); out = log_softmax(A_hat (h1@W2) + b2)
// R15: k_csr ELIMINATED. Buckets shrunk to 128 nodes (nb=782); aggregation is done
// per-bucket with fp32 LDS accumulators (stride-65 pad -> ~2-way banks, free) fed by
// ds_add_f32 with compile-time offsets; each thread walks one scatter-segment of the
// bucket. Self-loop = LDS init from own row. deg via global atomics in k_scatterL
// (+memsetAsync); dis = rsqrtf(deg+1) inline. Epilogues fuse bias+relu+gemm2 (L1)
// and bias+log_softmax (L2) with coalesced writes. h1 stays fp8 e4m3 (R14).
// 4 kernels + 1 memset. LDS-atomic order nondeterminism ~1e-6 (fp32) -- negligible.

#define F1 64
#define F2 16
#define BKT 128    // nodes per bucket; bucket = dst>>7, local = dst&127
#define NBKT 1024  // histogram array size (nb = 782)
#define NSB 256    // scatter blocks (== segments per bucket)
#define SBD 1024   // scatter block dim

typedef _Float16 f16x8 __attribute__((ext_vector_type(8)));
typedef float f32x2 __attribute__((ext_vector_type(2)));
typedef float f32x4 __attribute__((ext_vector_type(4)));

// convert 4 fp8(e4m3) packed in a dword and ds-atomic-add into p[0..3]
__device__ inline void acc4(float* p, unsigned v) {
  f32x2 lo = __builtin_amdgcn_cvt_pk_f32_fp8((int)v, false);
  f32x2 hi = __builtin_amdgcn_cvt_pk_f32_fp8((int)v, true);
  atomicAdd(p + 0, lo[0]);
  atomicAdd(p + 1, lo[1]);
  atomicAdd(p + 2, hi[0]);
  atomicAdd(p + 3, hi[1]);
}
// convert 4 fp8 and plain-store into p[0..3] (init path, pre-barrier)
__device__ inline void st4(float* p, unsigned v) {
  f32x2 lo = __builtin_amdgcn_cvt_pk_f32_fp8((int)v, false);
  f32x2 hi = __builtin_amdgcn_cvt_pk_f32_fp8((int)v, true);
  p[0] = lo[0]; p[1] = lo[1]; p[2] = hi[0]; p[3] = hi[1];
}

// ---- 1) per-block local counting sort into block-major tmp + segstart + deg ----
// Extra block (blockIdx == NSB) does the fp16 weight transpose instead.
__global__ void k_scatterL(const int* __restrict__ src, const int* __restrict__ dst,
                           int* __restrict__ tmp, int* __restrict__ segstart,
                           int* __restrict__ deg, int E, int nb, int chunk,
                           const float* __restrict__ W1, const float* __restrict__ W2,
                           __half* __restrict__ W1T, __half* __restrict__ W2T) {
  int t = threadIdx.x, sb = blockIdx.x;
  if (sb == NSB) {  // weight transpose block
    for (int i = t; i < 64 * 64; i += SBD) {
      int n = i >> 6, k = i & 63;
      W1T[i] = __float2half(W1[k * 64 + n]);
    }
    for (int i = t; i < 16 * 64; i += SBD) {
      int n = i >> 6, k = i & 63;
      W2T[i] = __float2half(W2[k * 16 + n]);
    }
    return;
  }
  __shared__ int h[NBKT];
  __shared__ int cur[NBKT];
  __shared__ int sc[NBKT];
  int beg = sb * chunk, end = min(beg + chunk, E);
  h[t] = 0;
  __syncthreads();
  int e;
  for (e = beg + t * 4; e + 4 <= end; e += 4 * SBD) {
    int4 d4 = *(const int4*)(dst + e);
    atomicAdd(&h[d4.x >> 7], 1);
    atomicAdd(&h[d4.y >> 7], 1);
    atomicAdd(&h[d4.z >> 7], 1);
    atomicAdd(&h[d4.w >> 7], 1);
    atomicAdd(&deg[d4.x], 1);
    atomicAdd(&deg[d4.y], 1);
    atomicAdd(&deg[d4.z], 1);
    atomicAdd(&deg[d4.w], 1);
  }
  for (; e < end; ++e) {
    int d = dst[e];
    atomicAdd(&h[d >> 7], 1);
    atomicAdd(&deg[d], 1);
  }
  __syncthreads();
  // exclusive scan of 1024 bins (Hillis-Steele, 1024 threads)
  sc[t] = h[t];
  __syncthreads();
  for (int off = 1; off < NBKT; off <<= 1) {
    int a = (t >= off) ? sc[t - off] : 0;
    __syncthreads();
    sc[t] += a;
    __syncthreads();
  }
  cur[t] = (t == 0) ? 0 : sc[t - 1];
  __syncthreads();
  if (t < nb) segstart[sb * (nb + 1) + t] = beg + cur[t];
  if (t == 0) segstart[sb * (nb + 1) + nb] = end;
  __syncthreads();
  // pass 2: place packed edges densely in [beg, end)
  for (e = beg + t * 4; e + 4 <= end; e += 4 * SBD) {
    int4 d4 = *(const int4*)(dst + e);
    int4 s4 = *(const int4*)(src + e);
    int b, off;
    b = d4.x >> 7; off = atomicAdd(&cur[b], 1); tmp[beg + off] = (s4.x << 7) | (d4.x & 127);
    b = d4.y >> 7; off = atomicAdd(&cur[b], 1); tmp[beg + off] = (s4.y << 7) | (d4.y & 127);
    b = d4.z >> 7; off = atomicAdd(&cur[b], 1); tmp[beg + off] = (s4.z << 7) | (d4.z & 127);
    b = d4.w >> 7; off = atomicAdd(&cur[b], 1); tmp[beg + off] = (s4.w << 7) | (d4.w & 127);
  }
  for (; e < end; ++e) {
    int d = dst[e];
    int b = d >> 7;
    int off = atomicAdd(&cur[b], 1);
    tmp[beg + off] = (src[e] << 7) | (d & 127);
  }
}

// ---- GEMM1 (MFMA): h1[n] = fp8(dis[n] * (x[n] @ W1)); 64 rows/block ----
__global__ void k_gemm1(const float* __restrict__ x, const __half* __restrict__ W1T,
                        const int* __restrict__ deg, unsigned char* __restrict__ out,
                        int N) {
  int t = threadIdx.x;
  int wv = t >> 6, lane = t & 63;
  int m = lane & 15, q = lane >> 4;  // quad
  int row0 = blockIdx.x * 64 + wv * 16;
  int arow = min(row0 + m, N - 1);  // clamp for load safety
  const _Float16* wt = (const _Float16*)W1T;
  f16x8 bf[4][2];
#pragma unroll
  for (int c = 0; c < 4; ++c)
#pragma unroll
    for (int kt = 0; kt < 2; ++kt)
      bf[c][kt] = *(const f16x8*)&wt[(c * 16 + m) * 64 + kt * 32 + q * 8];
  f16x8 a[2];
#pragma unroll
  for (int kt = 0; kt < 2; ++kt) {
    const float4* xp = (const float4*)(x + (size_t)arow * 64 + kt * 32 + q * 8);
    float4 u = xp[0], v = xp[1];
    a[kt][0] = (_Float16)u.x; a[kt][1] = (_Float16)u.y;
    a[kt][2] = (_Float16)u.z; a[kt][3] = (_Float16)u.w;
    a[kt][4] = (_Float16)v.x; a[kt][5] = (_Float16)v.y;
    a[kt][6] = (_Float16)v.z; a[kt][7] = (_Float16)v.w;
  }
  f32x4 acc[4] = {};
#pragma unroll
  for (int kt = 0; kt < 2; ++kt)
#pragma unroll
    for (int c = 0; c < 4; ++c)
      acc[c] = __builtin_amdgcn_mfma_f32_16x16x32_f16(a[kt], bf[c][kt], acc[c], 0, 0, 0);
  // epilogue: pack fp8 pairs (cols 2k,2k+1) via lane^1 exchange.
  // even-m lanes store c=0,1; odd-m lanes store c=2,3.
  bool even = (m & 1) == 0;
  int c0 = even ? 0 : 2;
#pragma unroll
  for (int r = 0; r < 4; ++r) {
    int n = row0 + q * 4 + r;
    int dg = deg[min(n, N - 1)];
    float dn = rsqrtf((float)(dg + 1));
    float v[4], pv[4];
#pragma unroll
    for (int c = 0; c < 4; ++c) v[c] = acc[c][r] * dn;
#pragma unroll
    for (int c = 0; c < 4; ++c) pv[c] = __shfl_xor(v[c], 1);
    if (n < N) {
#pragma unroll
      for (int k = 0; k < 2; ++k) {
        int c = c0 + k;
        float aa = even ? v[c] : pv[c];
        float bb = even ? pv[c] : v[c];
        int packed = __builtin_amdgcn_cvt_pk_fp8_f32(aa, bb, 0, false);
        *(unsigned short*)(out + (size_t)n * 64 + c * 16 + (m & ~1)) =
            (unsigned short)(packed & 0xffff);
      }
    }
  }
}

// ---- agg layer 1 (bucket-LDS accumulate) + bias/relu + fused GEMM2 -> h2 ----
// one block per 128-node bucket; 256 threads each walk one scatter-segment.
__global__ void k_bagg1(const unsigned char* __restrict__ h1,
                        const int* __restrict__ tmp, const int* __restrict__ segstart,
                        const int* __restrict__ deg, const float* __restrict__ b1,
                        const __half* __restrict__ W2T, __half* __restrict__ h2,
                        int N, int nb) {
  __shared__ float hacc[BKT * 65];  // stride 65: bank=(l+f)%32 -> ~2-way, free
  __shared__ float w2s[16 * 64];
  int b = blockIdx.x, t = threadIdx.x;  // 256 threads
  int node0 = b << 7;
  for (int i = t; i < 16 * 64; i += 256) w2s[i] = __half2float(W2T[i]);
  {  // self-loop init: 2 threads per node, 32 feats each (h1 pre-scaled by dis[n])
    int l = t >> 1, hf = t & 1;
    int n = node0 + l;
    if (n < N) {
      const uint4* rp = (const uint4*)(h1 + ((size_t)n << 6) + (hf << 5));
      uint4 r0 = rp[0], r1 = rp[1];
      float* p = hacc + l * 65 + hf * 32;
      st4(p + 0, r0.x);  st4(p + 4, r0.y);  st4(p + 8, r0.z);  st4(p + 12, r0.w);
      st4(p + 16, r1.x); st4(p + 20, r1.y); st4(p + 24, r1.z); st4(p + 28, r1.w);
    }
  }
  __syncthreads();
  int s0 = segstart[t * (nb + 1) + b];
  int len = segstart[t * (nb + 1) + b + 1] - s0;
  for (int i = 0; i < len; ++i) {
    int p = tmp[s0 + i];
    int srcr = p >> 7, l = p & 127;
    const uint4* rp = (const uint4*)(h1 + ((size_t)srcr << 6));
    uint4 r0 = rp[0], r1 = rp[1], r2 = rp[2], r3 = rp[3];
    float* q = hacc + l * 65;
    acc4(q + 0, r0.x);  acc4(q + 4, r0.y);  acc4(q + 8, r0.z);  acc4(q + 12, r0.w);
    acc4(q + 16, r1.x); acc4(q + 20, r1.y); acc4(q + 24, r1.z); acc4(q + 28, r1.w);
    acc4(q + 32, r2.x); acc4(q + 36, r2.y); acc4(q + 40, r2.z); acc4(q + 44, r2.w);
    acc4(q + 48, r3.x); acc4(q + 52, r3.y); acc4(q + 56, r3.z); acc4(q + 60, r3.w);
  }
  __syncthreads();
  // epilogue: y = relu(dis[n]*acc + b1); h2[n] = fp16(dis[n] * (y @ W2))
  int l = t >> 1, hf = t & 1;
  int n = node0 + l;
  if (n >= N) return;
  float dn = rsqrtf((float)(deg[n] + 1));
  const float* q = hacc + l * 65;
  float hr[64];
#pragma unroll
  for (int f = 0; f < 64; ++f) hr[f] = fmaxf(fmaf(dn, q[f], b1[f]), 0.f);
  f16x8 o;
#pragma unroll
  for (int jj = 0; jj < 8; ++jj) {
    const float* wr = w2s + (hf * 8 + jj) * 64;
    float s = 0.f;
#pragma unroll
    for (int f = 0; f < 64; ++f) s = fmaf(hr[f], wr[f], s);
    o[jj] = (_Float16)(s * dn);
  }
  *(f16x8*)((_Float16*)h2 + (size_t)n * 16 + hf * 8) = o;
}

// ---- agg layer 2 (bucket-LDS accumulate) + bias + log_softmax ----
__global__ void k_bagg2(const __half* __restrict__ h2, const int* __restrict__ tmp,
                        const int* __restrict__ segstart, const int* __restrict__ deg,
                        const float* __restrict__ b2, float* __restrict__ out,
                        int N, int nb) {
  __shared__ float acc2[BKT * 17];  // stride 17: bank=(17l+j)%32, 17 odd -> spread
  int b = blockIdx.x, t = threadIdx.x;
  int node0 = b << 7;
  const _Float16* hp = (const _Float16*)h2;
  {  // self-loop init
    int l = t >> 1, hf = t & 1;
    int n = node0 + l;
    if (n < N) {
      f16x8 r = *(const f16x8*)&hp[(size_t)n * 16 + hf * 8];
      float* p = acc2 + l * 17 + hf * 8;
#pragma unroll
      for (int k = 0; k < 8; ++k) p[k] = (float)r[k];
    }
  }
  __syncthreads();
  int s0 = segstart[t * (nb + 1) + b];
  int len = segstart[t * (nb + 1) + b + 1] - s0;
  for (int i = 0; i < len; ++i) {
    int p = tmp[s0 + i];
    int srcr = p >> 7, l = p & 127;
    f16x8 v0 = *(const f16x8*)&hp[(size_t)srcr * 16];
    f16x8 v1 = *(const f16x8*)&hp[(size_t)srcr * 16 + 8];
    float* q = acc2 + l * 17;
#pragma unroll
    for (int k = 0; k < 8; ++k) atomicAdd(q + k, (float)v0[k]);
#pragma unroll
    for (int k = 0; k < 8; ++k) atomicAdd(q + 8 + k, (float)v1[k]);
  }
  __syncthreads();
  int l = t >> 1, hf = t & 1;
  int n = node0 + l;
  if (n >= N) return;
  float dn = rsqrtf((float)(deg[n] + 1));
  const float* q = acc2 + l * 17 + hf * 8;
  float v[8];
#pragma unroll
  for (int k = 0; k < 8; ++k) v[k] = fmaf(dn, q[k], b2[hf * 8 + k]);
  float m = v[0];
#pragma unroll
  for (int k = 1; k < 8; ++k) m = fmaxf(m, v[k]);
  m = fmaxf(m, __shfl_xor(m, 1));  // combine with partner thread (same node)
  float s2 = 0.f;
#pragma unroll
  for (int k = 0; k < 8; ++k) s2 += __expf(v[k] - m);
  s2 += __shfl_xor(s2, 1);
  float ls = m + __logf(s2);
  float4 o0 = {v[0] - ls, v[1] - ls, v[2] - ls, v[3] - ls};
  float4 o1 = {v[4] - ls, v[5] - ls, v[6] - ls, v[7] - ls};
  float4* op = (float4*)(out + (size_t)n * 16 + hf * 8);
  op[0] = o0;
  op[1] = o1;
}

extern "C" void kernel_launch(void* const* d_in, const int* in_sizes, int n_in,
                              void* d_out, int out_size, void* d_ws, size_t ws_size,
                              hipStream_t stream) {
  const float* x = (const float*)d_in[0];
  const int* ei = (const int*)d_in[1];
  const float* W1 = (const float*)d_in[2];
  const float* b1 = (const float*)d_in[3];
  const float* W2 = (const float*)d_in[4];
  const float* b2 = (const float*)d_in[5];
  float* out = (float*)d_out;

  int N = in_sizes[0] / F1;  // 100000
  int E = in_sizes[1] / 2;   // 1600000
  const int* src = ei;
  const int* dst = ei + E;
  int nb = (N + BKT - 1) >> 7;  // 782 buckets
  int chunk = ((E + NSB - 1) / NSB + 3) & ~3;  // 6252

  char* ws = (char*)d_ws;
  size_t o_w1t = 0;                                                   // 64*64 fp16
  size_t o_w2t = o_w1t + 64 * 64 * 2;                                 // 16*64 fp16
  size_t o_seg = (o_w2t + 16 * 64 * 2 + 255) & ~(size_t)255;          // NSB*(nb+1) int
  size_t o_deg = (o_seg + (size_t)NSB * (nb + 1) * 4 + 255) & ~(size_t)255;  // N int
  size_t o_tmp = (o_deg + (size_t)N * 4 + 255) & ~(size_t)255;        // NSB*chunk int
  size_t o_h1  = (o_tmp + (size_t)NSB * chunk * 4 + 255) & ~(size_t)255;  // N*64 fp8
  size_t o_h2  = (o_h1 + (size_t)N * 64 + 255) & ~(size_t)255;        // N*16 fp16

  __half* W1T = (__half*)(ws + o_w1t);
  __half* W2T = (__half*)(ws + o_w2t);
  int* segst  = (int*)(ws + o_seg);
  int* deg    = (int*)(ws + o_deg);
  int* tmp    = (int*)(ws + o_tmp);
  unsigned char* h1 = (unsigned char*)(ws + o_h1);
  __half* h2  = (__half*)(ws + o_h2);

  hipMemsetAsync(deg, 0, (size_t)N * 4, stream);
  k_scatterL<<<NSB + 1, SBD, 0, stream>>>(src, dst, tmp, segst, deg, E, nb, chunk,
                                          W1, W2, W1T, W2T);
  int gb = (N + 63) / 64;  // 1563
  k_gemm1<<<gb, 256, 0, stream>>>(x, W1T, deg, h1, N);
  k_bagg1<<<nb, 256, 0, stream>>>(h1, tmp, segst, deg, b1, W2T, h2, N, nb);
  k_bagg2<<<nb, 256, 0, stream>>>(h2, tmp, segst, deg, b2, out, N, nb);
}

// Round 4
// 181.054 us; speedup vs baseline: 5.8084x; 5.8084x over previous
//
#include <hip/hip_runtime.h>
#include <hip/hip_bf16.h>
#include <hip/hip_fp16.h>

// GCN 2-layer: h1 = relu(A_hat (x@W1) + b1); out = log_softmax(A_hat (h1@W2) + b2)
// R16: revert to R13 pull-model pipeline (k_scatterL -> k_csr -> gemm1 -> agg1f -> agg2);
// R15's push-LDS bucket accumulate serialized on same-address ds_add collisions (705us).
// h1 stored fp8 e4m3 in PERMUTED feature order: byte 4m+j of a row holds feature 16j+m.
// gemm1's MFMA thread (owns features {m,16+m,32+m,48+m}) packs its 4 values into ONE
// dword via 2x v_cvt_pk_fp8_f32 (no shuffles) and stores one coalesced dword/row.
// Permutation absorbed by staged b1p / W2Tp (built in the free weight-transpose block).
// fp32 accumulation everywhere (order-insensitive under nondeterministic CSR order).

#define F1 64
#define F2 16
#define NBKT 256  // bucket array size (nb = 196)
#define BSH 512   // nodes per bucket; bucket = dst>>9, local = dst&511
#define NSB 256   // scatter blocks (== segments per bucket)
#define SBD 1024  // scatter block dim
#define STG 9216  // stage capacity (mean 8192, sigma ~90)

typedef _Float16 f16x8 __attribute__((ext_vector_type(8)));
typedef _Float16 f16x4 __attribute__((ext_vector_type(4)));
typedef float f32x2 __attribute__((ext_vector_type(2)));
typedef float f32x4 __attribute__((ext_vector_type(4)));
typedef float f32x8 __attribute__((ext_vector_type(8)));

__device__ inline f32x8 shfl_xor_f32x8(f32x8 v, int off) {
  f32x8 r;
#pragma unroll
  for (int k = 0; k < 8; ++k) r[k] = __shfl_xor(v[k], off);
  return r;
}
__device__ inline f32x4 shfl_xor_f32x4(f32x4 v, int off) {
  f32x4 r;
#pragma unroll
  for (int k = 0; k < 4; ++k) r[k] = __shfl_xor(v[k], off);
  return r;
}

// accumulate 8 fp8 (e4m3) features into f32x8 via packed converts
__device__ inline void acc_fp8x8(f32x8& a, uint2 v) {
  f32x2 p0 = __builtin_amdgcn_cvt_pk_f32_fp8((int)v.x, false);
  f32x2 p1 = __builtin_amdgcn_cvt_pk_f32_fp8((int)v.x, true);
  f32x2 p2 = __builtin_amdgcn_cvt_pk_f32_fp8((int)v.y, false);
  f32x2 p3 = __builtin_amdgcn_cvt_pk_f32_fp8((int)v.y, true);
  a[0] += p0[0]; a[1] += p0[1]; a[2] += p1[0]; a[3] += p1[1];
  a[4] += p2[0]; a[5] += p2[1]; a[6] += p3[0]; a[7] += p3[1];
}

// ---- 1) per-block local counting sort into block-major tmp + segstart ----
// Extra block (blockIdx == NSB) stages W1T, permuted W2Tp, permuted b1p.
__global__ void k_scatterL(const int* __restrict__ src, const int* __restrict__ dst,
                           int* __restrict__ tmp, int* __restrict__ segstart,
                           int E, int nb, int chunk,
                           const float* __restrict__ W1, const float* __restrict__ W2,
                           const float* __restrict__ b1,
                           __half* __restrict__ W1T, __half* __restrict__ W2Tp,
                           float* __restrict__ b1p) {
  int t = threadIdx.x, sb = blockIdx.x;
  if (sb == NSB) {  // weight staging block
    for (int i = t; i < 64 * 64; i += SBD) {
      int n = i >> 6, k = i & 63;
      W1T[i] = __float2half(W1[k * 64 + n]);
    }
    // W2Tp[j*64 + p] = W2[f(p)][j], f(p) = 16*(p&3) + (p>>2)
    for (int i = t; i < 16 * 64; i += SBD) {
      int j = i >> 6, p = i & 63;
      int fp = 16 * (p & 3) + (p >> 2);
      W2Tp[i] = __float2half(W2[fp * 16 + j]);
    }
    if (t < 64) b1p[t] = b1[16 * (t & 3) + (t >> 2)];
    return;
  }
  __shared__ int h[NBKT];
  __shared__ int cur[NBKT];
  __shared__ int sc[NBKT];
  int beg = sb * chunk, end = min(beg + chunk, E);
  for (int i = t; i < NBKT; i += SBD) h[i] = 0;
  __syncthreads();
  int e;
  for (e = beg + t * 4; e + 4 <= end; e += 4 * SBD) {
    int4 d4 = *(const int4*)(dst + e);
    atomicAdd(&h[d4.x >> 9], 1);
    atomicAdd(&h[d4.y >> 9], 1);
    atomicAdd(&h[d4.z >> 9], 1);
    atomicAdd(&h[d4.w >> 9], 1);
  }
  for (; e < end; ++e) atomicAdd(&h[dst[e] >> 9], 1);
  __syncthreads();
  // exclusive scan of 256 bins (first 256 threads own 1 bin each)
  if (t < NBKT) sc[t] = h[t];
  __syncthreads();
  for (int off = 1; off < NBKT; off <<= 1) {
    int a = (t < NBKT && t >= off) ? sc[t - off] : 0;
    __syncthreads();
    if (t < NBKT) sc[t] += a;
    __syncthreads();
  }
  if (t < NBKT) cur[t] = (t == 0) ? 0 : sc[t - 1];
  __syncthreads();
  for (int i = t; i < nb; i += SBD) segstart[sb * (nb + 1) + i] = beg + cur[i];
  if (t == 0) segstart[sb * (nb + 1) + nb] = end;
  __syncthreads();
  // pass 2: place packed edges densely in [beg, end)
  for (e = beg + t * 4; e + 4 <= end; e += 4 * SBD) {
    int4 d4 = *(const int4*)(dst + e);
    int4 s4 = *(const int4*)(src + e);
    int b, off;
    b = d4.x >> 9; off = atomicAdd(&cur[b], 1); tmp[beg + off] = (s4.x << 9) | (d4.x & 511);
    b = d4.y >> 9; off = atomicAdd(&cur[b], 1); tmp[beg + off] = (s4.y << 9) | (d4.y & 511);
    b = d4.z >> 9; off = atomicAdd(&cur[b], 1); tmp[beg + off] = (s4.z << 9) | (d4.z & 511);
    b = d4.w >> 9; off = atomicAdd(&cur[b], 1); tmp[beg + off] = (s4.w << 9) | (d4.w & 511);
  }
  for (; e < end; ++e) {
    int d = dst[e];
    int b = d >> 9;
    int off = atomicAdd(&cur[b], 1);
    tmp[beg + off] = (src[e] << 9) | (d & 511);
  }
}

// ---- 2) per-bucket single-pass LDS-staged sort -> csr + rowptr + dis ----
__global__ void k_csr(const int* __restrict__ tmp, const int* __restrict__ segstart,
                      int* __restrict__ csr, int* __restrict__ rowptr,
                      float* __restrict__ dis, int N, int nb, int chunk) {
  __shared__ int stage[STG];
  __shared__ int sc[BSH];
  __shared__ int cnt[BSH];
  __shared__ int lofs[BSH];
  __shared__ int s_beg;
  int b = blockIdx.x, t = threadIdx.x;  // 512 threads
  // segment of scatter-block t (t < NSB)
  int s0 = 0, len = 0;
  if (t < NSB) {
    s0 = segstart[t * (nb + 1) + b];
    len = segstart[t * (nb + 1) + b + 1] - s0;
  }
  // bbase reduction: sum over t of (s0 - t*chunk)
  sc[t] = (t < NSB) ? (s0 - t * chunk) : 0;
  __syncthreads();
  for (int off = BSH / 2; off > 0; off >>= 1) {
    if (t < off) sc[t] += sc[t + off];
    __syncthreads();
  }
  if (t == 0) s_beg = sc[0];
  __syncthreads();
  int beg = s_beg;
  // seg-length scan for stage offsets
  sc[t] = (t < NSB) ? len : 0;
  __syncthreads();
  for (int off = 1; off < NSB; off <<= 1) {
    int a = (t < NSB && t >= off) ? sc[t - off] : 0;
    __syncthreads();
    if (t < NSB) sc[t] += a;
    __syncthreads();
  }
  int total = sc[NSB - 1];
  int my0 = (t == 0) ? 0 : ((t < NSB) ? sc[t - 1] : 0);
  // stage this bucket's edges into LDS (single global read of tmp)
  if (t < NSB) {
    int i = 0;
    for (; i + 4 <= len; i += 4) {
      int v0 = tmp[s0 + i], v1 = tmp[s0 + i + 1], v2 = tmp[s0 + i + 2], v3 = tmp[s0 + i + 3];
      stage[my0 + i] = v0; stage[my0 + i + 1] = v1;
      stage[my0 + i + 2] = v2; stage[my0 + i + 3] = v3;
    }
    for (; i < len; ++i) stage[my0 + i] = tmp[s0 + i];
  }
  cnt[t] = 0;
  __syncthreads();
  for (int i = t; i < total; i += BSH) atomicAdd(&cnt[stage[i] & (BSH - 1)], 1);
  __syncthreads();
  sc[t] = cnt[t];
  __syncthreads();
  for (int off = 1; off < BSH; off <<= 1) {
    int a = (t >= off) ? sc[t - off] : 0;
    __syncthreads();
    sc[t] += a;
    __syncthreads();
  }
  int excl = (t == 0) ? 0 : sc[t - 1];
  lofs[t] = excl;
  int n = b * BSH + t;
  if (n <= N) rowptr[n] = beg + excl;  // n==N lands on E
  if (n < N) dis[n] = rsqrtf((float)(cnt[t] + 1));
  cnt[t] = 0;  // reuse as cursor
  __syncthreads();
  for (int i = t; i < total; i += BSH) {
    int p = stage[i];
    int l = p & (BSH - 1);
    int off = atomicAdd(&cnt[l], 1);
    csr[beg + lofs[l] + off] = p >> 9;
  }
}

// ---- GEMM1 (MFMA): h1[n] = fp8_perm(dis[n] * (x[n] @ W1)); 64 rows/block ----
// permuted store: byte 4m+j of row n holds feature 16j+m -> one dword/thread/row
__global__ void k_gemm1(const float* __restrict__ x, const __half* __restrict__ W1T,
                        const float* __restrict__ dis, unsigned char* __restrict__ out,
                        int N) {
  int t = threadIdx.x;
  int wv = t >> 6, lane = t & 63;
  int m = lane & 15, q = lane >> 4;  // quad
  int row0 = blockIdx.x * 64 + wv * 16;
  int arow = min(row0 + m, N - 1);  // clamp for load safety
  const _Float16* wt = (const _Float16*)W1T;
  f16x8 bf[4][2];
#pragma unroll
  for (int c = 0; c < 4; ++c)
#pragma unroll
    for (int kt = 0; kt < 2; ++kt)
      bf[c][kt] = *(const f16x8*)&wt[(c * 16 + m) * 64 + kt * 32 + q * 8];
  f16x8 a[2];
#pragma unroll
  for (int kt = 0; kt < 2; ++kt) {
    const float4* xp = (const float4*)(x + (size_t)arow * 64 + kt * 32 + q * 8);
    float4 u = xp[0], v = xp[1];
    a[kt][0] = (_Float16)u.x; a[kt][1] = (_Float16)u.y;
    a[kt][2] = (_Float16)u.z; a[kt][3] = (_Float16)u.w;
    a[kt][4] = (_Float16)v.x; a[kt][5] = (_Float16)v.y;
    a[kt][6] = (_Float16)v.z; a[kt][7] = (_Float16)v.w;
  }
  f32x4 acc[4] = {};
#pragma unroll
  for (int kt = 0; kt < 2; ++kt)
#pragma unroll
    for (int c = 0; c < 4; ++c)
      acc[c] = __builtin_amdgcn_mfma_f32_16x16x32_f16(a[kt], bf[c][kt], acc[c], 0, 0, 0);
#pragma unroll
  for (int r = 0; r < 4; ++r) {
    int n = row0 + q * 4 + r;
    if (n < N) {
      float dn = dis[n];
      int d = __builtin_amdgcn_cvt_pk_fp8_f32(acc[0][r] * dn, acc[1][r] * dn, 0, false);
      d = __builtin_amdgcn_cvt_pk_fp8_f32(acc[2][r] * dn, acc[3][r] * dn, d, true);
      *(unsigned int*)(out + (size_t)n * 64 + m * 4) = (unsigned)d;
    }
  }
}

// ---- agg layer 1 + fused GEMM2: 2 nodes/wave (half=32 lanes: 4 subs x 8 fl) ----
// h1 rows are 64 B fp8 (permuted feature order); fp32 accumulate via packed cvt.
// b1p / W2Tp are in the same permuted order, so the math is unchanged.
__global__ void k_agg1f(const unsigned char* __restrict__ h, const float* __restrict__ dis,
                        const int* __restrict__ rowptr, const int* __restrict__ csr,
                        const float* __restrict__ b1p, const __half* __restrict__ W2Tp,
                        __half* __restrict__ h2, int N) {
  int gt = blockIdx.x * blockDim.x + threadIdx.x;
  int w = gt >> 6;
  int lane = gt & 63;
  int half = lane >> 5;         // node within wave
  int sub = (lane >> 3) & 3;    // 4 edge substreams per node
  int fl = lane & 7;            // feature-octet lane
  int n = w * 2 + half;
  if (n >= N) return;
  float dn = dis[n];
  float4 bu = *(const float4*)(b1p + fl * 8);
  float4 bv = *(const float4*)(b1p + fl * 8 + 4);
  const _Float16* wt = (const _Float16*)W2Tp;
  // 4 outputs per sub: j = sub*4 + i
  f16x8 wj[4];
#pragma unroll
  for (int i = 0; i < 4; ++i)
    wj[i] = *(const f16x8*)&wt[(sub * 4 + i) * 64 + fl * 8];
  f32x8 acc0 = {}, acc1 = {};
  if (sub == 0)  // self loop (rows pre-scaled by dis)
    acc_fp8x8(acc0, *(const uint2*)&h[(size_t)n * 64 + fl * 8]);
  int beg = rowptr[n], end = rowptr[n + 1];
  int e = beg + sub;
  int sA = (e < end) ? csr[e] : -1;
  int sB = (e + 4 < end) ? csr[e + 4] : -1;
  while (sB >= 0) {
    int e2 = e + 8;
    int sC = (e2 < end) ? csr[e2] : -1;
    int sD = (e2 + 4 < end) ? csr[e2 + 4] : -1;
    uint2 v0 = *(const uint2*)&h[(size_t)sA * 64 + fl * 8];
    uint2 v1 = *(const uint2*)&h[(size_t)sB * 64 + fl * 8];
    acc_fp8x8(acc0, v0);
    acc_fp8x8(acc1, v1);
    sA = sC; sB = sD; e = e2;
  }
  if (sA >= 0)
    acc_fp8x8(acc0, *(const uint2*)&h[(size_t)sA * 64 + fl * 8]);
  f32x8 acc = acc0 + acc1;
  // reduce across the 4 substreams (stay within 32-lane half), fp32
  acc += shfl_xor_f32x8(acc, 8);
  acc += shfl_xor_f32x8(acc, 16);
  // bias + relu in fp32
  float bb[8] = {bu.x, bu.y, bu.z, bu.w, bv.x, bv.y, bv.z, bv.w};
  float hr[8];
#pragma unroll
  for (int k = 0; k < 8; ++k)
    hr[k] = fmaxf(fmaf(dn, acc[k], bb[k]), 0.f);
  // fused gemm2 in fp32: outputs j = sub*4 .. sub*4+3
  float p[4];
#pragma unroll
  for (int i = 0; i < 4; ++i) {
    float s = 0.f;
#pragma unroll
    for (int k = 0; k < 8; ++k) s = fmaf(hr[k], (float)wj[i][k], s);
    s += __shfl_xor(s, 1);
    s += __shfl_xor(s, 2);
    s += __shfl_xor(s, 4);
    p[i] = s;
  }
  if (fl == 0) {
    f16x4 o;
#pragma unroll
    for (int i = 0; i < 4; ++i) o[i] = (_Float16)(p[i] * dn);
    *(f16x4*)((_Float16*)h2 + (size_t)n * 16 + sub * 4) = o;
  }
}

// ---- agg layer 2 + bias + log_softmax: 2 nodes/wave (8 subs x 4 fl per node) ----
__global__ void k_agg2(const __half* __restrict__ h2, const float* __restrict__ dis,
                       const int* __restrict__ rowptr, const int* __restrict__ csr,
                       const float* __restrict__ b2, float* __restrict__ out, int N) {
  int gt = blockIdx.x * blockDim.x + threadIdx.x;
  int w = gt >> 6;
  int lane = gt & 63;
  int half = lane >> 5;
  int sub = (lane >> 2) & 7;  // 8 edge substreams per node
  int fl = lane & 3;          // feature-quad lane
  int n = w * 2 + half;
  if (n >= N) return;
  const _Float16* hp = (const _Float16*)h2;
  f32x4 acc0 = {}, acc1 = {};
  if (sub == 0)  // self loop
    acc0 = __builtin_convertvector(*(const f16x4*)&hp[(size_t)n * 16 + fl * 4], f32x4);
  int beg = rowptr[n], end = rowptr[n + 1];
  int e = beg + sub;
  int sA = (e < end) ? csr[e] : -1;
  int sB = (e + 8 < end) ? csr[e + 8] : -1;
  while (sB >= 0) {
    int e2 = e + 16;
    int sC = (e2 < end) ? csr[e2] : -1;
    int sD = (e2 + 8 < end) ? csr[e2 + 8] : -1;
    f16x4 v0 = *(const f16x4*)&hp[(size_t)sA * 16 + fl * 4];
    f16x4 v1 = *(const f16x4*)&hp[(size_t)sB * 16 + fl * 4];
    acc0 += __builtin_convertvector(v0, f32x4);
    acc1 += __builtin_convertvector(v1, f32x4);
    sA = sC; sB = sD; e = e2;
  }
  if (sA >= 0)
    acc0 += __builtin_convertvector(*(const f16x4*)&hp[(size_t)sA * 16 + fl * 4], f32x4);
  f32x4 acc = acc0 + acc1;
  // reduce across 8 substreams (within half), fp32
  acc += shfl_xor_f32x4(acc, 4);
  acc += shfl_xor_f32x4(acc, 8);
  acc += shfl_xor_f32x4(acc, 16);
  if (sub == 0) {
    float dn = dis[n];
    float4 bb = *(const float4*)(b2 + fl * 4);
    float v0 = fmaf(dn, acc[0], bb.x);
    float v1 = fmaf(dn, acc[1], bb.y);
    float v2 = fmaf(dn, acc[2], bb.z);
    float v3 = fmaf(dn, acc[3], bb.w);
    float m = fmaxf(fmaxf(v0, v1), fmaxf(v2, v3));
    m = fmaxf(m, __shfl_xor(m, 1));
    m = fmaxf(m, __shfl_xor(m, 2));
    float s2 = __expf(v0 - m) + __expf(v1 - m) + __expf(v2 - m) + __expf(v3 - m);
    s2 += __shfl_xor(s2, 1);
    s2 += __shfl_xor(s2, 2);
    float ls = m + __logf(s2);
    float4 o = {v0 - ls, v1 - ls, v2 - ls, v3 - ls};
    *(float4*)(out + (size_t)n * 16 + fl * 4) = o;
  }
}

extern "C" void kernel_launch(void* const* d_in, const int* in_sizes, int n_in,
                              void* d_out, int out_size, void* d_ws, size_t ws_size,
                              hipStream_t stream) {
  const float* x = (const float*)d_in[0];
  const int* ei = (const int*)d_in[1];
  const float* W1 = (const float*)d_in[2];
  const float* b1 = (const float*)d_in[3];
  const float* W2 = (const float*)d_in[4];
  const float* b2 = (const float*)d_in[5];
  float* out = (float*)d_out;

  int N = in_sizes[0] / F1;  // 100000
  int E = in_sizes[1] / 2;   // 1600000
  const int* src = ei;
  const int* dst = ei + E;
  int nb = (N + BSH - 1) >> 9;  // 196 buckets
  int chunk = ((E + NSB - 1) / NSB + 3) & ~3;  // 6252

  char* ws = (char*)d_ws;
  size_t o_w1t = 0;                                                   // 64*64 fp16
  size_t o_w2t = o_w1t + 64 * 64 * 2;                                 // 16*64 fp16
  size_t o_b1p = (o_w2t + 16 * 64 * 2 + 255) & ~(size_t)255;          // 64 f32
  size_t o_seg = (o_b1p + 64 * 4 + 255) & ~(size_t)255;               // NSB*(nb+1) int
  size_t o_dis = (o_seg + (size_t)NSB * (nb + 1) * 4 + 255) & ~(size_t)255;  // N f32
  size_t o_rowp = (o_dis + (size_t)N * 4 + 255) & ~(size_t)255;       // N+1 int
  size_t o_tmp = (o_rowp + (size_t)(N + 1) * 4 + 255) & ~(size_t)255; // NSB*chunk int
  size_t o_csr = (o_tmp + (size_t)NSB * chunk * 4 + 255) & ~(size_t)255;  // E int
  size_t o_h1 = (o_csr + (size_t)E * 4 + 255) & ~(size_t)255;         // N*64 fp8
  size_t o_h2 = (o_h1 + (size_t)N * 64 + 255) & ~(size_t)255;         // N*16 fp16

  __half* W1T = (__half*)(ws + o_w1t);
  __half* W2Tp = (__half*)(ws + o_w2t);
  float* b1p = (float*)(ws + o_b1p);
  int* segst = (int*)(ws + o_seg);
  float* dis = (float*)(ws + o_dis);
  int* rowptr = (int*)(ws + o_rowp);
  int* tmp = (int*)(ws + o_tmp);
  int* csr = (int*)(ws + o_csr);
  unsigned char* h1 = (unsigned char*)(ws + o_h1);
  __half* h2 = (__half*)(ws + o_h2);

  k_scatterL<<<NSB + 1, SBD, 0, stream>>>(src, dst, tmp, segst, E, nb, chunk,
                                          W1, W2, b1, W1T, W2Tp, b1p);
  k_csr<<<nb, BSH, 0, stream>>>(tmp, segst, csr, rowptr, dis, N, nb, chunk);

  int gb = (N + 63) / 64;  // 1563
  k_gemm1<<<gb, 256, 0, stream>>>(x, W1T, dis, h1, N);
  int aw = (N + 1) / 2;  // waves for 2-node-per-wave agg kernels
  k_agg1f<<<((size_t)aw * 64 + 255) / 256, 256, 0, stream>>>(h1, dis, rowptr, csr, b1p, W2Tp, h2, N);
  k_agg2<<<((size_t)aw * 64 + 255) / 256, 256, 0, stream>>>(h2, dis, rowptr, csr, b2, out, N);
}